// Round 12
// baseline (335.078 us; speedup 1.0000x reference)
//
#include <hip/hip_runtime.h>
#include <hip/hip_bf16.h>

#define NS_    48
#define NV_    10
#define N_NODE 20000
#define N_EDGE 100000
#define HID    144     // 3*NS
#define OUTC   58      // 48 + 10
#define ODIM   78      // 48 + 30
#define TILE   64
#define NTILES 1563    // ceil(100000/64)
#define LDE    160     // padded K (144->160), LDS row stride (bf16 elems)
#define WNUM   2784

// prep_all grid layout: [0,1920) prep_g, [1920,2010) prep_fc1, [2010,2401) hist
#define PG_BLKS   1920
#define PF_BLKS   90
#define PH_BLKS   391

typedef __attribute__((ext_vector_type(8))) short bf8;
typedef __attribute__((ext_vector_type(4))) float f32x4;

__device__ __forceinline__ short f2bf(float x) {
  __hip_bfloat16 h = __float2bfloat16(x);
  union { __hip_bfloat16 b; short s; } u; u.b = h; return u.s;
}
__device__ __forceinline__ unsigned pk2(float a, float b) {
  return (unsigned)(unsigned short)f2bf(a) | ((unsigned)(unsigned short)f2bf(b) << 16);
}

// ---------------- fused prep: G frags + fc1 frags + src histogram ----------------
__global__ void prep_all(const float* __restrict__ fc1_w, const float* __restrict__ fc2_w,
                         const float* __restrict__ fc2_b, const int* __restrict__ eidx,
                         short* __restrict__ fc1frag, short* __restrict__ gfrag,
                         int* __restrict__ cnt) {
  const int b = blockIdx.x;
  if (b < PG_BLKS) {
    // G frags: [i 48][strip 4][ks 5][lane][j]; row k==144 carries fc2_b
    int idx = b * 256 + threadIdx.x;
    int j = idx & 7, l = (idx >> 3) & 63, t = idx >> 9;
    int ks = t % 5, u = t / 5;
    int strip = u & 3, i = u >> 2;
    int k = ks * 32 + ((l >> 4) << 3) + j;
    int c = strip * 16 + (l & 15);
    float v = 0.f;
    if (c < OUTC) {
      if (k < HID)
        v = (c < NS_) ? fc2_w[k * WNUM + i * NS_ + c]
                      : fc2_w[k * WNUM + NS_ * NS_ + i * NV_ + (c - NS_)];
      else if (k == HID)
        v = (c < NS_) ? fc2_b[i * NS_ + c]
                      : fc2_b[NS_ * NS_ + i * NV_ + (c - NS_)];
    }
    gfrag[idx] = f2bf(v);
  } else if (b < PG_BLKS + PF_BLKS) {
    // fc1 frags: [nt 9][ks 5][lane 64][j 8]
    int idx = (b - PG_BLKS) * 256 + threadIdx.x;
    if (idx >= 9 * 5 * 512) return;
    int j = idx & 7, l = (idx >> 3) & 63, t = idx >> 9;
    int ks = t % 5, nt = t / 5;
    int k = ks * 32 + ((l >> 4) << 3) + j;
    int n = nt * 16 + (l & 15);
    fc1frag[idx] = f2bf(k < HID ? fc1_w[k * HID + n] : 0.f);
  } else {
    int e = (b - PG_BLKS - PF_BLKS) * 256 + threadIdx.x;
    if (e < N_EDGE) atomicAdd(&cnt[eidx[e]], 1);
  }
}

// ---------------- CSR build: counting sort of edges by src ----------------
__global__ void k_scan1(const int* __restrict__ cnt, int* __restrict__ locexc,
                        int* __restrict__ blksum) {
  __shared__ int sh[256];
  int g = blockIdx.x * 256 + threadIdx.x;
  int v = (g < N_NODE) ? cnt[g] : 0;
  sh[threadIdx.x] = v;
  __syncthreads();
  for (int d = 1; d < 256; d <<= 1) {
    int t = (threadIdx.x >= d) ? sh[threadIdx.x - d] : 0;
    __syncthreads();
    sh[threadIdx.x] += t;
    __syncthreads();
  }
  if (g < N_NODE) locexc[g] = sh[threadIdx.x] - v;
  if (threadIdx.x == 255) blksum[blockIdx.x] = sh[255];
}

__global__ void k_scan2(const int* __restrict__ blksum, int* __restrict__ blkoff) {
  __shared__ int sh[128];
  int t = threadIdx.x;
  int v = (t < 79) ? blksum[t] : 0;
  sh[t] = v;
  __syncthreads();
  for (int d = 1; d < 128; d <<= 1) {
    int x = (t >= d) ? sh[t - d] : 0;
    __syncthreads();
    sh[t] += x;
    __syncthreads();
  }
  if (t < 79) blkoff[t] = sh[t] - v;
}

__global__ void k_scatter(const int* __restrict__ eidx, const int* __restrict__ locexc,
                          const int* __restrict__ blkoff, int* __restrict__ cursor,
                          int* __restrict__ sortedE) {
  int e = blockIdx.x * 256 + threadIdx.x;
  if (e >= N_EDGE) return;
  int s = eidx[e];
  int base = blkoff[s >> 8] + locexc[s];
  int r = atomicAdd(&cursor[s], 1);
  sortedE[base + r] = e;
}

// ---------------- main fused kernel: 64 sorted edges per WG, 4 waves ----------------
// R9 structure (best: 141 us) with __launch_bounds__(256, 4): VGPR cap 128 (measured 84),
// LDS 4x34.8=139KB <= 160KB -> 4 blocks/CU (was 3). Occupancy is the measured lever:
// occ 10/18/27% -> dur 203/173/141 us across R6/R11/R9.
__global__ __launch_bounds__(256, 4) void fused_edge(
    const float* __restrict__ node_attr, const int* __restrict__ eidx,
    const float* __restrict__ edge_attr, const float* __restrict__ edge_sh,
    const float* __restrict__ fc1_b, const int* __restrict__ sortedE,
    const short* __restrict__ gfrag, const short* __restrict__ fc1frag,
    float* __restrict__ out)
{
  __shared__ short EA[TILE * LDE];   // ea tile -> H tile -> O tile (float[64][80])
  __shared__ float xT[NS_ * TILE];   // x transposed: xT[i][e]
  __shared__ float shs[TILE * 4];    // edge_sh cols 0..3
  __shared__ int   srcs[TILE];       // sorted srcs (-1 for invalid rows)
  __shared__ int   runStart[TILE + 1], runSrc[TILE];
  __shared__ int   nRunsSh;

  const int tid  = threadIdx.x;
  const int lane = tid & 63;
  const int wv   = tid >> 6;
  const int base = blockIdx.x * TILE;

  // zero K-pad cols 144..159
  for (int t = tid; t < TILE * 16; t += 256) {
    int r = t >> 4, c = t & 15;
    EA[r * LDE + HID + c] = 0;
  }

  // ---- gather (src-sorted edge ids): 4 threads per edge, 12 cols each ----
  {
    const int el = tid >> 2, part = tid & 3;
    const int gi = base + el;
    const bool ev = gi < N_EDGE;
    const int e  = ev ? sortedE[gi] : 0;
    const int es = ev ? eidx[e] : 0;
    const int ed = ev ? eidx[N_EDGE + e] : 0;
    if (part == 0) {
      srcs[el] = ev ? es : -1;
      #pragma unroll
      for (int c = 0; c < 4; ++c) shs[el * 4 + c] = ev ? edge_sh[(size_t)e * 9 + c] : 0.f;
    }
    const float4* pa = (const float4*)(edge_attr + (size_t)e * NS_);
    const float4* ps = (const float4*)(node_attr + (size_t)es * NS_);
    const float4* pd = (const float4*)(node_attr + (size_t)ed * NS_);
    const float4 z4 = make_float4(0.f, 0.f, 0.f, 0.f);
    #pragma unroll
    for (int q = 0; q < 3; ++q) {
      const int c0 = part * 12 + q * 4;
      float4 va = ev ? pa[part * 3 + q] : z4;
      float4 vs = ev ? ps[part * 3 + q] : z4;
      float4 vd = ev ? pd[part * 3 + q] : z4;
      *(uint2*)&EA[el * LDE + c0]           = make_uint2(pk2(va.x, va.y), pk2(va.z, va.w));
      *(uint2*)&EA[el * LDE + NS_ + c0]     = make_uint2(pk2(vs.x, vs.y), pk2(vs.z, vs.w));
      *(uint2*)&EA[el * LDE + 2 * NS_ + c0] = make_uint2(pk2(vd.x, vd.y), pk2(vd.z, vd.w));
      xT[(c0 + 0) * TILE + el] = vd.x;
      xT[(c0 + 1) * TILE + el] = vd.y;
      xT[(c0 + 2) * TILE + el] = vd.z;
      xT[(c0 + 3) * TILE + el] = vd.w;
    }
  }
  __syncthreads();

  // ---- fc1: wave wv computes H rows [wv*16, wv*16+16); H overwrites EA in place ----
  {
    const int mrow = lane & 15;
    const int koff = (lane >> 4) << 3;
    bf8 aF[5];
    #pragma unroll
    for (int ks = 0; ks < 5; ++ks)
      aF[ks] = *(const bf8*)&EA[(wv * 16 + mrow) * LDE + ks * 32 + koff];
    #pragma unroll
    for (int nt = 0; nt < 9; ++nt) {
      f32x4 acc = {0.f, 0.f, 0.f, 0.f};
      #pragma unroll
      for (int ks = 0; ks < 5; ++ks) {
        bf8 bF = *(const bf8*)&fc1frag[((nt * 5 + ks) * 64 + lane) * 8];
        acc = __builtin_amdgcn_mfma_f32_16x16x32_bf16(aF[ks], bF, acc, 0, 0, 0);
      }
      const int col = nt * 16 + mrow;
      const float bb = fc1_b[col];
      #pragma unroll
      for (int r = 0; r < 4; ++r) {
        float h = acc[r] + bb;
        h = h > 0.f ? h : 0.f;
        EA[(wv * 16 + ((lane >> 4) << 2) + r) * LDE + col] = f2bf(h);
      }
    }
    if (lane < 16) EA[(wv * 16 + lane) * LDE + HID] = (short)0x3F80;  // 1.0 col for bias
  }
  __syncthreads();

  // ---- phase 2: wave wv owns output cols [wv*16, wv*16+16) for all 64 edges ----
  {
    const int mrow = lane & 15;
    const int koff = (lane >> 4) << 3;
    const int g0 = (lane >> 4) << 2;

    f32x4 oacc[4];
    #pragma unroll
    for (int mt = 0; mt < 4; ++mt) oacc[mt] = (f32x4){0.f, 0.f, 0.f, 0.f};

    // hoist A-fragments of H (reused 48x); pin against rematerialization
    bf8 aF[4][5];
    #pragma unroll
    for (int mt = 0; mt < 4; ++mt)
      #pragma unroll
      for (int ks = 0; ks < 5; ++ks) {
        aF[mt][ks] = *(const bf8*)&EA[(mt * 16 + mrow) * LDE + ks * 32 + koff];
        asm volatile("" : "+v"(aF[mt][ks]));
      }
    __syncthreads();  // all waves done reading EA -> safe to alias as O later

    const short* gb = gfrag + wv * 2560 + lane * 8;
    auto loadB = [&](bf8 (&BF)[5], int i) {
      const short* p = gb + i * 10240;
      #pragma unroll
      for (int ks = 0; ks < 5; ++ks) BF[ks] = *(const bf8*)(p + ks * 512);
    };
    auto compute = [&](const bf8 (&BF)[5], int i) {
      #pragma unroll
      for (int mt = 0; mt < 4; ++mt) {
        f32x4 wi = {0.f, 0.f, 0.f, 0.f};
        #pragma unroll
        for (int ks = 0; ks < 5; ++ks)
          wi = __builtin_amdgcn_mfma_f32_16x16x32_bf16(aF[mt][ks], BF[ks], wi, 0, 0, 0);
        const float4 xs = *(const float4*)&xT[i * TILE + mt * 16 + g0];
        oacc[mt][0] += xs.x * wi[0];
        oacc[mt][1] += xs.y * wi[1];
        oacc[mt][2] += xs.z * wi[2];
        oacc[mt][3] += xs.w * wi[3];
      }
    };

    // i-loop rotated per block (R9): concurrent blocks read different G_i slices
    const int roff = (int)(blockIdx.x % (unsigned)NS_);
    auto rot = [&](int i) { int r = i + roff; return (r >= NS_) ? r - NS_ : r; };

    bf8 bA[5], bB[5];
    loadB(bA, rot(0));
    for (int i = 0; i < NS_; i += 2) {
      loadB(bB, rot(i + 1));
      compute(bA, rot(i));
      loadB(bA, rot((i + 2 < NS_) ? i + 2 : NS_ - 1));
      compute(bB, rot(i + 1));
    }

    // ---- epilogue: scale into LDS O tile (aliases EA), run-reduce, few atomics ----
    float* O = (float*)EA;  // [64][80] f32 = 20480 B, exactly EA's size
    const float nrm = 0.14433756729740643f;  // 1/sqrt(48)
    const int col = wv * 16 + mrow;
    #pragma unroll
    for (int mt = 0; mt < 4; ++mt) {
      #pragma unroll
      for (int r = 0; r < 4; ++r) {
        const int row = mt * 16 + g0 + r;
        const float v = oacc[mt][r] * nrm;
        if (col < NS_) {
          O[row * 80 + col] = v * shs[row * 4 + 0];
        } else if (col < OUTC) {
          const int kp = col - NS_;
          O[row * 80 + NS_ + kp * 3 + 0] = v * shs[row * 4 + 1];
          O[row * 80 + NS_ + kp * 3 + 1] = v * shs[row * 4 + 2];
          O[row * 80 + NS_ + kp * 3 + 2] = v * shs[row * 4 + 3];
        }
      }
    }
  }
  __syncthreads();

  // run detection over sorted srcs (wave 0)
  if (tid < 64) {
    const int s = srcs[tid];
    const bool valid = s >= 0;
    const bool head = valid && (tid == 0 || srcs[tid - 1] != s);
    const unsigned long long hm = __ballot(head);
    const unsigned long long vm = __ballot(valid);
    const int rank = __popcll(hm & ((1ull << tid) - 1ull));
    if (head) { runStart[rank] = tid; runSrc[rank] = s; }
    if (tid == 0) {
      const int nR = __popcll(hm);
      nRunsSh = nR;
      runStart[nR] = __popcll(vm);  // valid rows form a prefix
    }
  }
  __syncthreads();

  {
    const float* O = (const float*)EA;
    const int nR = nRunsSh;
    for (int t = tid; t < nR * ODIM; t += 256) {
      const int k = t / ODIM, c = t - k * ODIM;
      const int rs = runStart[k], re = runStart[k + 1];
      float s = 0.f;
      for (int r = rs; r < re; ++r) s += O[r * 80 + c];
      atomicAdd(&out[(size_t)runSrc[k] * ODIM + c], s);
    }
  }
}

__global__ void finalize(float* __restrict__ out, const int* __restrict__ cnt) {
  int idx = blockIdx.x * 256 + threadIdx.x;
  if (idx >= N_NODE * ODIM) return;
  int n = idx / ODIM;
  out[idx] = out[idx] / fmaxf((float)cnt[n], 1.f);
}

extern "C" void kernel_launch(void* const* d_in, const int* in_sizes, int n_in,
                              void* d_out, int out_size, void* d_ws, size_t ws_size,
                              hipStream_t stream) {
  (void)in_sizes; (void)n_in; (void)out_size; (void)ws_size;
  const float* node_attr = (const float*)d_in[0];
  const int*   eidx      = (const int*)d_in[1];
  const float* edge_attr = (const float*)d_in[2];
  const float* edge_sh   = (const float*)d_in[3];
  const float* fc1_w     = (const float*)d_in[4];
  const float* fc1_b     = (const float*)d_in[5];
  const float* fc2_w     = (const float*)d_in[6];
  const float* fc2_b     = (const float*)d_in[7];
  float* out = (float*)d_out;

  char* ws = (char*)d_ws;
  short* gfrag   = (short*)(ws);                    // 983040 B
  short* fc1frag = (short*)(ws + 983040);           // 46080 B
  int*   cnt     = (int*)(ws + 1029120);            // 80000 B
  int*   locexc  = (int*)(ws + 1109120);            // 80000 B
  int*   cursor  = (int*)(ws + 1189120);            // 80000 B
  int*   blksum  = (int*)(ws + 1269120);            // 512 B
  int*   blkoff  = (int*)(ws + 1269632);            // 512 B
  int*   sortedE = (int*)(ws + 1270144);            // 400000 B

  hipMemsetAsync(out, 0, (size_t)N_NODE * ODIM * sizeof(float), stream);
  hipMemsetAsync(cnt, 0, N_NODE * sizeof(int), stream);
  hipMemsetAsync(cursor, 0, N_NODE * sizeof(int), stream);

  prep_all<<<PG_BLKS + PF_BLKS + PH_BLKS, 256, 0, stream>>>(
      fc1_w, fc2_w, fc2_b, eidx, fc1frag, gfrag, cnt);

  k_scan1<<<(N_NODE + 255) / 256, 256, 0, stream>>>(cnt, locexc, blksum);
  k_scan2<<<1, 128, 0, stream>>>(blksum, blkoff);
  k_scatter<<<(N_EDGE + 255) / 256, 256, 0, stream>>>(eidx, locexc, blkoff, cursor, sortedE);

  fused_edge<<<NTILES, 256, 0, stream>>>(
      node_attr, eidx, edge_attr, edge_sh, fc1_b, sortedE, gfrag, fc1frag, out);

  finalize<<<(N_NODE * ODIM + 255) / 256, 256, 0, stream>>>(out, cnt);
}

// Round 13
// 166.975 us; speedup vs baseline: 2.0068x; 2.0068x over previous
//
#include <hip/hip_runtime.h>
#include <hip/hip_bf16.h>

#define NS_    48
#define NV_    10
#define N_NODE 20000
#define N_EDGE 100000
#define HID    144     // 3*NS
#define OUTC   58      // 48 + 10
#define ODIM   78      // 48 + 30
#define TILE   64
#define NTILES 1563    // ceil(100000/64)
#define LDE    160     // padded K (144->160), LDS row stride (bf16 elems)
#define WNUM   2784

// prep_all grid layout: [0,1920) prep_g, [1920,2010) prep_fc1, [2010,2401) hist
#define PG_BLKS   1920
#define PF_BLKS   90
#define PH_BLKS   391

typedef __attribute__((ext_vector_type(8))) short bf8;
typedef __attribute__((ext_vector_type(4))) float f32x4;

__device__ __forceinline__ short f2bf(float x) {
  __hip_bfloat16 h = __float2bfloat16(x);
  union { __hip_bfloat16 b; short s; } u; u.b = h; return u.s;
}
__device__ __forceinline__ unsigned pk2(float a, float b) {
  return (unsigned)(unsigned short)f2bf(a) | ((unsigned)(unsigned short)f2bf(b) << 16);
}

// ---------------- fused prep: G frags + fc1 frags + src histogram ----------------
__global__ void prep_all(const float* __restrict__ fc1_w, const float* __restrict__ fc2_w,
                         const float* __restrict__ fc2_b, const int* __restrict__ eidx,
                         short* __restrict__ fc1frag, short* __restrict__ gfrag,
                         int* __restrict__ cnt) {
  const int b = blockIdx.x;
  if (b < PG_BLKS) {
    // G frags: [i 48][strip 4][ks 5][lane][j]; row k==144 carries fc2_b
    int idx = b * 256 + threadIdx.x;
    int j = idx & 7, l = (idx >> 3) & 63, t = idx >> 9;
    int ks = t % 5, u = t / 5;
    int strip = u & 3, i = u >> 2;
    int k = ks * 32 + ((l >> 4) << 3) + j;
    int c = strip * 16 + (l & 15);
    float v = 0.f;
    if (c < OUTC) {
      if (k < HID)
        v = (c < NS_) ? fc2_w[k * WNUM + i * NS_ + c]
                      : fc2_w[k * WNUM + NS_ * NS_ + i * NV_ + (c - NS_)];
      else if (k == HID)
        v = (c < NS_) ? fc2_b[i * NS_ + c]
                      : fc2_b[NS_ * NS_ + i * NV_ + (c - NS_)];
    }
    gfrag[idx] = f2bf(v);
  } else if (b < PG_BLKS + PF_BLKS) {
    // fc1 frags: [nt 9][ks 5][lane 64][j 8]
    int idx = (b - PG_BLKS) * 256 + threadIdx.x;
    if (idx >= 9 * 5 * 512) return;
    int j = idx & 7, l = (idx >> 3) & 63, t = idx >> 9;
    int ks = t % 5, nt = t / 5;
    int k = ks * 32 + ((l >> 4) << 3) + j;
    int n = nt * 16 + (l & 15);
    fc1frag[idx] = f2bf(k < HID ? fc1_w[k * HID + n] : 0.f);
  } else {
    int e = (b - PG_BLKS - PF_BLKS) * 256 + threadIdx.x;
    if (e < N_EDGE) atomicAdd(&cnt[eidx[e]], 1);
  }
}

// ---------------- CSR build: counting sort of edges by src ----------------
__global__ void k_scan1(const int* __restrict__ cnt, int* __restrict__ locexc,
                        int* __restrict__ blksum) {
  __shared__ int sh[256];
  int g = blockIdx.x * 256 + threadIdx.x;
  int v = (g < N_NODE) ? cnt[g] : 0;
  sh[threadIdx.x] = v;
  __syncthreads();
  for (int d = 1; d < 256; d <<= 1) {
    int t = (threadIdx.x >= d) ? sh[threadIdx.x - d] : 0;
    __syncthreads();
    sh[threadIdx.x] += t;
    __syncthreads();
  }
  if (g < N_NODE) locexc[g] = sh[threadIdx.x] - v;
  if (threadIdx.x == 255) blksum[blockIdx.x] = sh[255];
}

__global__ void k_scan2(const int* __restrict__ blksum, int* __restrict__ blkoff) {
  __shared__ int sh[128];
  int t = threadIdx.x;
  int v = (t < 79) ? blksum[t] : 0;
  sh[t] = v;
  __syncthreads();
  for (int d = 1; d < 128; d <<= 1) {
    int x = (t >= d) ? sh[t - d] : 0;
    __syncthreads();
    sh[t] += x;
    __syncthreads();
  }
  if (t < 79) blkoff[t] = sh[t] - v;
}

__global__ void k_scatter(const int* __restrict__ eidx, const int* __restrict__ locexc,
                          const int* __restrict__ blkoff, int* __restrict__ cursor,
                          int* __restrict__ sortedE) {
  int e = blockIdx.x * 256 + threadIdx.x;
  if (e >= N_EDGE) return;
  int s = eidx[e];
  int base = blkoff[s >> 8] + locexc[s];
  int r = atomicAdd(&cursor[s], 1);
  sortedE[base + r] = e;
}

// ---------------- main fused kernel: 64 sorted edges per WG, 4 waves ----------------
// EXACT R9 configuration (best measured: 141 us). __launch_bounds__(256, 3) is the
// proven register sweet spot: VGPR 84, no spill. (256,4)/(512,4) clamp to 64 -> 400MB
// spill (R10/R12); do not raise the min-waves arg.
__global__ __launch_bounds__(256, 3) void fused_edge(
    const float* __restrict__ node_attr, const int* __restrict__ eidx,
    const float* __restrict__ edge_attr, const float* __restrict__ edge_sh,
    const float* __restrict__ fc1_b, const int* __restrict__ sortedE,
    const short* __restrict__ gfrag, const short* __restrict__ fc1frag,
    float* __restrict__ out)
{
  __shared__ short EA[TILE * LDE];   // ea tile -> H tile -> O tile (float[64][80])
  __shared__ float xT[NS_ * TILE];   // x transposed: xT[i][e]
  __shared__ float shs[TILE * 4];    // edge_sh cols 0..3
  __shared__ int   srcs[TILE];       // sorted srcs (-1 for invalid rows)
  __shared__ int   runStart[TILE + 1], runSrc[TILE];
  __shared__ int   nRunsSh;

  const int tid  = threadIdx.x;
  const int lane = tid & 63;
  const int wv   = tid >> 6;
  const int base = blockIdx.x * TILE;

  // zero K-pad cols 144..159
  for (int t = tid; t < TILE * 16; t += 256) {
    int r = t >> 4, c = t & 15;
    EA[r * LDE + HID + c] = 0;
  }

  // ---- gather (src-sorted edge ids): 4 threads per edge, 12 cols each ----
  {
    const int el = tid >> 2, part = tid & 3;
    const int gi = base + el;
    const bool ev = gi < N_EDGE;
    const int e  = ev ? sortedE[gi] : 0;
    const int es = ev ? eidx[e] : 0;
    const int ed = ev ? eidx[N_EDGE + e] : 0;
    if (part == 0) {
      srcs[el] = ev ? es : -1;
      #pragma unroll
      for (int c = 0; c < 4; ++c) shs[el * 4 + c] = ev ? edge_sh[(size_t)e * 9 + c] : 0.f;
    }
    const float4* pa = (const float4*)(edge_attr + (size_t)e * NS_);
    const float4* ps = (const float4*)(node_attr + (size_t)es * NS_);
    const float4* pd = (const float4*)(node_attr + (size_t)ed * NS_);
    const float4 z4 = make_float4(0.f, 0.f, 0.f, 0.f);
    #pragma unroll
    for (int q = 0; q < 3; ++q) {
      const int c0 = part * 12 + q * 4;
      float4 va = ev ? pa[part * 3 + q] : z4;
      float4 vs = ev ? ps[part * 3 + q] : z4;
      float4 vd = ev ? pd[part * 3 + q] : z4;
      *(uint2*)&EA[el * LDE + c0]           = make_uint2(pk2(va.x, va.y), pk2(va.z, va.w));
      *(uint2*)&EA[el * LDE + NS_ + c0]     = make_uint2(pk2(vs.x, vs.y), pk2(vs.z, vs.w));
      *(uint2*)&EA[el * LDE + 2 * NS_ + c0] = make_uint2(pk2(vd.x, vd.y), pk2(vd.z, vd.w));
      xT[(c0 + 0) * TILE + el] = vd.x;
      xT[(c0 + 1) * TILE + el] = vd.y;
      xT[(c0 + 2) * TILE + el] = vd.z;
      xT[(c0 + 3) * TILE + el] = vd.w;
    }
  }
  __syncthreads();

  // ---- fc1: wave wv computes H rows [wv*16, wv*16+16); H overwrites EA in place ----
  {
    const int mrow = lane & 15;
    const int koff = (lane >> 4) << 3;
    bf8 aF[5];
    #pragma unroll
    for (int ks = 0; ks < 5; ++ks)
      aF[ks] = *(const bf8*)&EA[(wv * 16 + mrow) * LDE + ks * 32 + koff];
    #pragma unroll
    for (int nt = 0; nt < 9; ++nt) {
      f32x4 acc = {0.f, 0.f, 0.f, 0.f};
      #pragma unroll
      for (int ks = 0; ks < 5; ++ks) {
        bf8 bF = *(const bf8*)&fc1frag[((nt * 5 + ks) * 64 + lane) * 8];
        acc = __builtin_amdgcn_mfma_f32_16x16x32_bf16(aF[ks], bF, acc, 0, 0, 0);
      }
      const int col = nt * 16 + mrow;
      const float bb = fc1_b[col];
      #pragma unroll
      for (int r = 0; r < 4; ++r) {
        float h = acc[r] + bb;
        h = h > 0.f ? h : 0.f;
        EA[(wv * 16 + ((lane >> 4) << 2) + r) * LDE + col] = f2bf(h);
      }
    }
    if (lane < 16) EA[(wv * 16 + lane) * LDE + HID] = (short)0x3F80;  // 1.0 col for bias
  }
  __syncthreads();

  // ---- phase 2: wave wv owns output cols [wv*16, wv*16+16) for all 64 edges ----
  {
    const int mrow = lane & 15;
    const int koff = (lane >> 4) << 3;
    const int g0 = (lane >> 4) << 2;

    f32x4 oacc[4];
    #pragma unroll
    for (int mt = 0; mt < 4; ++mt) oacc[mt] = (f32x4){0.f, 0.f, 0.f, 0.f};

    // hoist A-fragments of H (reused 48x); pin against rematerialization
    bf8 aF[4][5];
    #pragma unroll
    for (int mt = 0; mt < 4; ++mt)
      #pragma unroll
      for (int ks = 0; ks < 5; ++ks) {
        aF[mt][ks] = *(const bf8*)&EA[(mt * 16 + mrow) * LDE + ks * 32 + koff];
        asm volatile("" : "+v"(aF[mt][ks]));
      }
    __syncthreads();  // all waves done reading EA -> safe to alias as O later

    const short* gb = gfrag + wv * 2560 + lane * 8;
    auto loadB = [&](bf8 (&BF)[5], int i) {
      const short* p = gb + i * 10240;
      #pragma unroll
      for (int ks = 0; ks < 5; ++ks) BF[ks] = *(const bf8*)(p + ks * 512);
    };
    auto compute = [&](const bf8 (&BF)[5], int i) {
      #pragma unroll
      for (int mt = 0; mt < 4; ++mt) {
        f32x4 wi = {0.f, 0.f, 0.f, 0.f};
        #pragma unroll
        for (int ks = 0; ks < 5; ++ks)
          wi = __builtin_amdgcn_mfma_f32_16x16x32_bf16(aF[mt][ks], BF[ks], wi, 0, 0, 0);
        const float4 xs = *(const float4*)&xT[i * TILE + mt * 16 + g0];
        oacc[mt][0] += xs.x * wi[0];
        oacc[mt][1] += xs.y * wi[1];
        oacc[mt][2] += xs.z * wi[2];
        oacc[mt][3] += xs.w * wi[3];
      }
    };

    // i-loop rotated per block (R9): concurrent blocks read different G_i slices
    const int roff = (int)(blockIdx.x % (unsigned)NS_);
    auto rot = [&](int i) { int r = i + roff; return (r >= NS_) ? r - NS_ : r; };

    bf8 bA[5], bB[5];
    loadB(bA, rot(0));
    for (int i = 0; i < NS_; i += 2) {
      loadB(bB, rot(i + 1));
      compute(bA, rot(i));
      loadB(bA, rot((i + 2 < NS_) ? i + 2 : NS_ - 1));
      compute(bB, rot(i + 1));
    }

    // ---- epilogue: scale into LDS O tile (aliases EA), run-reduce, few atomics ----
    float* O = (float*)EA;  // [64][80] f32 = 20480 B, exactly EA's size
    const float nrm = 0.14433756729740643f;  // 1/sqrt(48)
    const int col = wv * 16 + mrow;
    #pragma unroll
    for (int mt = 0; mt < 4; ++mt) {
      #pragma unroll
      for (int r = 0; r < 4; ++r) {
        const int row = mt * 16 + g0 + r;
        const float v = oacc[mt][r] * nrm;
        if (col < NS_) {
          O[row * 80 + col] = v * shs[row * 4 + 0];
        } else if (col < OUTC) {
          const int kp = col - NS_;
          O[row * 80 + NS_ + kp * 3 + 0] = v * shs[row * 4 + 1];
          O[row * 80 + NS_ + kp * 3 + 1] = v * shs[row * 4 + 2];
          O[row * 80 + NS_ + kp * 3 + 2] = v * shs[row * 4 + 3];
        }
      }
    }
  }
  __syncthreads();

  // run detection over sorted srcs (wave 0)
  if (tid < 64) {
    const int s = srcs[tid];
    const bool valid = s >= 0;
    const bool head = valid && (tid == 0 || srcs[tid - 1] != s);
    const unsigned long long hm = __ballot(head);
    const unsigned long long vm = __ballot(valid);
    const int rank = __popcll(hm & ((1ull << tid) - 1ull));
    if (head) { runStart[rank] = tid; runSrc[rank] = s; }
    if (tid == 0) {
      const int nR = __popcll(hm);
      nRunsSh = nR;
      runStart[nR] = __popcll(vm);  // valid rows form a prefix
    }
  }
  __syncthreads();

  {
    const float* O = (const float*)EA;
    const int nR = nRunsSh;
    for (int t = tid; t < nR * ODIM; t += 256) {
      const int k = t / ODIM, c = t - k * ODIM;
      const int rs = runStart[k], re = runStart[k + 1];
      float s = 0.f;
      for (int r = rs; r < re; ++r) s += O[r * 80 + c];
      atomicAdd(&out[(size_t)runSrc[k] * ODIM + c], s);
    }
  }
}

__global__ void finalize(float* __restrict__ out, const int* __restrict__ cnt) {
  int idx = blockIdx.x * 256 + threadIdx.x;
  if (idx >= N_NODE * ODIM) return;
  int n = idx / ODIM;
  out[idx] = out[idx] / fmaxf((float)cnt[n], 1.f);
}

extern "C" void kernel_launch(void* const* d_in, const int* in_sizes, int n_in,
                              void* d_out, int out_size, void* d_ws, size_t ws_size,
                              hipStream_t stream) {
  (void)in_sizes; (void)n_in; (void)out_size; (void)ws_size;
  const float* node_attr = (const float*)d_in[0];
  const int*   eidx      = (const int*)d_in[1];
  const float* edge_attr = (const float*)d_in[2];
  const float* edge_sh   = (const float*)d_in[3];
  const float* fc1_w     = (const float*)d_in[4];
  const float* fc1_b     = (const float*)d_in[5];
  const float* fc2_w     = (const float*)d_in[6];
  const float* fc2_b     = (const float*)d_in[7];
  float* out = (float*)d_out;

  char* ws = (char*)d_ws;
  short* gfrag   = (short*)(ws);                    // 983040 B
  short* fc1frag = (short*)(ws + 983040);           // 46080 B
  int*   cnt     = (int*)(ws + 1029120);            // 80000 B
  int*   locexc  = (int*)(ws + 1109120);            // 80000 B
  int*   cursor  = (int*)(ws + 1189120);            // 80000 B
  int*   blksum  = (int*)(ws + 1269120);            // 512 B
  int*   blkoff  = (int*)(ws + 1269632);            // 512 B
  int*   sortedE = (int*)(ws + 1270144);            // 400000 B

  hipMemsetAsync(out, 0, (size_t)N_NODE * ODIM * sizeof(float), stream);
  hipMemsetAsync(cnt, 0, N_NODE * sizeof(int), stream);
  hipMemsetAsync(cursor, 0, N_NODE * sizeof(int), stream);

  prep_all<<<PG_BLKS + PF_BLKS + PH_BLKS, 256, 0, stream>>>(
      fc1_w, fc2_w, fc2_b, eidx, fc1frag, gfrag, cnt);

  k_scan1<<<(N_NODE + 255) / 256, 256, 0, stream>>>(cnt, locexc, blksum);
  k_scan2<<<1, 128, 0, stream>>>(blksum, blkoff);
  k_scatter<<<(N_EDGE + 255) / 256, 256, 0, stream>>>(eidx, locexc, blkoff, cursor, sortedE);

  fused_edge<<<NTILES, 256, 0, stream>>>(
      node_attr, eidx, edge_attr, edge_sh, fc1_b, sortedE, gfrag, fc1frag, out);

  finalize<<<(N_NODE * ODIM + 255) / 256, 256, 0, stream>>>(out, cnt);
}